// Round 13
// baseline (67270.502 us; speedup 1.0000x reference)
//
#include <hip/hip_runtime.h>

#define HN 256
#define QN 64
#define PN 512
#define CH 8

typedef float f4 __attribute__((ext_vector_type(4)));

__device__ __forceinline__ float dot4(f4 a, f4 b) {
  return a.x * b.x + a.y * b.y + a.z * b.z + a.w * b.w;
}
__device__ __forceinline__ float fast_sig(float x) {
  return __builtin_amdgcn_rcpf(1.f + __builtin_amdgcn_exp2f(-1.44269504f * x));
}
__device__ __forceinline__ float fast_tanh(float x) {
  return 1.f - 2.f * __builtin_amdgcn_rcpf(1.f + __builtin_amdgcn_exp2f(2.88539008f * x));
}
__device__ __forceinline__ float red16(float v) {
  v += __shfl_xor(v, 1); v += __shfl_xor(v, 2);
  v += __shfl_xor(v, 4); v += __shfl_xor(v, 8);
  return v;
}
__device__ __forceinline__ f4 red16v(f4 v) {
  v.x = red16(v.x); v.y = red16(v.y); v.z = red16(v.z); v.w = red16(v.w);
  return v;
}

struct SMem {
  alignas(16) float q32[QN][HN];        // 64KB PERSISTENT (Phase D reads it)
  union {
    float wqt[QN][HN + 4];              // 65KB prologue-only wq table
    struct {
      alignas(16) float pgc[CH][1024];  // 32KB  bias + Wih[:,0:256] @ p_u
      alignas(16) float wpc[CH][HN];    // 8KB   whp_b + whp_w @ p_u
      alignas(16) float pch[CH][HN];    // 8KB   p rows (f32)
    } c;
  } u;
  alignas(16) float hx[HN];
  float cx[HN];
  alignas(16) float wA[HN];
  float wrb[HN];                        // whr_b staged
  alignas(16) float attn[HN];
  float gates[1024];
  float scores[QN];
  alignas(16) float al[QN];
};
static_assert(sizeof(SMem) <= 160 * 1024, "LDS overflow");
static_assert(sizeof(SMem) > 80 * 1024, "want exactly 1 block/CU");

__global__ void __launch_bounds__(1024)
match_kernel(const float* __restrict__ passage, const float* __restrict__ question,
             const float* __restrict__ whq_w, const float* __restrict__ whq_b,
             const float* __restrict__ whp_w, const float* __restrict__ whp_b,
             const float* __restrict__ whr_w, const float* __restrict__ whr_b,
             const float* __restrict__ w_w,
             const float* __restrict__ Wih_f, const float* __restrict__ Whh_f,
             const float* __restrict__ bih_f, const float* __restrict__ bhh_f,
             const float* __restrict__ Wih_b, const float* __restrict__ Whh_b,
             const float* __restrict__ bih_b, const float* __restrict__ bhh_b,
             float* __restrict__ out)
{
  __shared__ SMem sm;
  const int t = threadIdx.x;
  const int bid = blockIdx.x;
  // dir-homogeneous XCD mapping: XCD = bid%8; XCD 0-3 -> dir0, 4-7 -> dir1
  const int e = bid & 7;
  const int dir = e >> 2;
  const int b = ((bid >> 3) << 2) | (e & 3);

  const float* Wih = dir ? Wih_b : Wih_f;
  const float* Whh = dir ? Whh_b : Whh_f;
  const float* bih = dir ? bih_b : bih_f;
  const float* bhh = dir ? bhh_b : bhh_f;

  const int qB = t >> 4;   // 0..63 (phase B q-owner; also row-group base g2)
  const int sg = t & 15;   // 16-lane slice id
  const int g2 = t >> 4;   // row-group base for sliced GEMVs

  // ---------------- prologue 1: stage question[b], init state ----------------
  {
    const int q = t >> 4, c0 = (t & 15) * 16;
    const float* src = question + ((size_t)b * QN + q) * HN + c0;
    #pragma unroll
    for (int m = 0; m < 4; ++m)
      *(f4*)&sm.q32[q][c0 + 4 * m] = *(const f4*)(src + 4 * m);
  }
  if (t < HN) {
    sm.hx[t] = 0.f; sm.cx[t] = 0.f;
    sm.wrb[t] = whr_b[t];
  }
  __syncthreads();

  // ---- prologue 2a: wqt[q][h] = whq_b[h] + sum_k Q[q][k]*whq_w[h][k] ----
  // (r12-verified) h = t&255, group (t>>8) handles 16 q's; acc in named f4s.
  {
    const int h = t & 255, qh = (t >> 8) * 16;
    const float qb = whq_b[h];
    f4 ac0, ac1, ac2, ac3;
    ac0.x = ac0.y = ac0.z = ac0.w = qb;
    ac1 = ac0; ac2 = ac0; ac3 = ac0;
    const float* wrow = whq_w + (size_t)h * HN;
    for (int k = 0; k < HN; k += 4) {
      f4 w4 = *(const f4*)(wrow + k);
      #define WQ4(V, Q0) \
        V.x += dot4(w4, *(const f4*)&sm.q32[qh + (Q0) + 0][k]); \
        V.y += dot4(w4, *(const f4*)&sm.q32[qh + (Q0) + 1][k]); \
        V.z += dot4(w4, *(const f4*)&sm.q32[qh + (Q0) + 2][k]); \
        V.w += dot4(w4, *(const f4*)&sm.q32[qh + (Q0) + 3][k]);
      WQ4(ac0, 0) WQ4(ac1, 4) WQ4(ac2, 8) WQ4(ac3, 12)
      #undef WQ4
    }
    sm.u.wqt[qh + 0][h] = ac0.x;  sm.u.wqt[qh + 1][h] = ac0.y;
    sm.u.wqt[qh + 2][h] = ac0.z;  sm.u.wqt[qh + 3][h] = ac0.w;
    sm.u.wqt[qh + 4][h] = ac1.x;  sm.u.wqt[qh + 5][h] = ac1.y;
    sm.u.wqt[qh + 6][h] = ac1.z;  sm.u.wqt[qh + 7][h] = ac1.w;
    sm.u.wqt[qh + 8][h] = ac2.x;  sm.u.wqt[qh + 9][h] = ac2.y;
    sm.u.wqt[qh + 10][h] = ac2.z; sm.u.wqt[qh + 11][h] = ac2.w;
    sm.u.wqt[qh + 12][h] = ac3.x; sm.u.wqt[qh + 13][h] = ac3.y;
    sm.u.wqt[qh + 14][h] = ac3.z; sm.u.wqt[qh + 15][h] = ac3.w;
  }
  __syncthreads();

  // ---- prologue 2b: per-thread wq/w_w slices -> 8 named f4 registers ----
  f4 wq0 = *(const f4*)&sm.u.wqt[qB][sg * 16 + 0];
  f4 wq1 = *(const f4*)&sm.u.wqt[qB][sg * 16 + 4];
  f4 wq2 = *(const f4*)&sm.u.wqt[qB][sg * 16 + 8];
  f4 wq3 = *(const f4*)&sm.u.wqt[qB][sg * 16 + 12];
  f4 ww0 = *(const f4*)(w_w + sg * 16 + 0);
  f4 ww1 = *(const f4*)(w_w + sg * 16 + 4);
  f4 ww2 = *(const f4*)(w_w + sg * 16 + 8);
  f4 ww3 = *(const f4*)(w_w + sg * 16 + 12);
  const int rE = g2 + 64 * sg;          // the single gate row this thread writes
  const float biasE = bih[rE] + bhh[rE];
  __syncthreads();   // wqt reads done; union becomes chunk area

  const int tb = dir ? (PN - 1) : 0;
  const int ts = dir ? -1 : 1;

  for (int s = 0; s < PN; ++s) {
    const int tau = s & (CH - 1);
    if (tau == 0) {
      // ---- stage p chunk ----
      if (t < 512) {
        const int tt = t >> 6, cc = (t & 63) * 4;
        const int trow = tb + ts * (s + tt);
        *(f4*)&sm.u.c.pch[tt][cc] =
            *(const f4*)(passage + ((size_t)b * PN + trow) * HN + cc);
      }
      __syncthreads();
      // ---- wpc[u][h] = whp_b[h] + whp_w[h].p_u (4 sliced passes) ----
      #pragma unroll
      for (int rr = 0; rr < 4; ++rr) {
        const int h = g2 + 64 * rr;
        const float* wrow = whp_w + (size_t)h * HN + sg * 4;
        f4 wa0 = {0.f, 0.f, 0.f, 0.f}, wa1 = wa0;
        #pragma unroll
        for (int m = 0; m < 4; ++m) {
          f4 w = *(const f4*)(wrow + m * 64);
          wa0.x += dot4(w, *(const f4*)&sm.u.c.pch[0][m * 64 + sg * 4]);
          wa0.y += dot4(w, *(const f4*)&sm.u.c.pch[1][m * 64 + sg * 4]);
          wa0.z += dot4(w, *(const f4*)&sm.u.c.pch[2][m * 64 + sg * 4]);
          wa0.w += dot4(w, *(const f4*)&sm.u.c.pch[3][m * 64 + sg * 4]);
          wa1.x += dot4(w, *(const f4*)&sm.u.c.pch[4][m * 64 + sg * 4]);
          wa1.y += dot4(w, *(const f4*)&sm.u.c.pch[5][m * 64 + sg * 4]);
          wa1.z += dot4(w, *(const f4*)&sm.u.c.pch[6][m * 64 + sg * 4]);
          wa1.w += dot4(w, *(const f4*)&sm.u.c.pch[7][m * 64 + sg * 4]);
        }
        wa0 = red16v(wa0); wa1 = red16v(wa1);
        if (sg == rr) {
          const float pb = whp_b[h];
          sm.u.c.wpc[0][h] = wa0.x + pb; sm.u.c.wpc[1][h] = wa0.y + pb;
          sm.u.c.wpc[2][h] = wa0.z + pb; sm.u.c.wpc[3][h] = wa0.w + pb;
          sm.u.c.wpc[4][h] = wa1.x + pb; sm.u.c.wpc[5][h] = wa1.y + pb;
          sm.u.c.wpc[6][h] = wa1.z + pb; sm.u.c.wpc[7][h] = wa1.w + pb;
        }
      }
      // ---- pgc[u][r] = biasE + Wih[r, 0:256].p_u (16 sliced passes) ----
      #pragma unroll
      for (int rr = 0; rr < 16; ++rr) {
        const int r = g2 + 64 * rr;
        const float* wrow = Wih + (size_t)r * 512 + sg * 4;
        f4 pa0 = {0.f, 0.f, 0.f, 0.f}, pa1 = pa0;
        #pragma unroll
        for (int m = 0; m < 4; ++m) {
          f4 w = *(const f4*)(wrow + m * 64);
          pa0.x += dot4(w, *(const f4*)&sm.u.c.pch[0][m * 64 + sg * 4]);
          pa0.y += dot4(w, *(const f4*)&sm.u.c.pch[1][m * 64 + sg * 4]);
          pa0.z += dot4(w, *(const f4*)&sm.u.c.pch[2][m * 64 + sg * 4]);
          pa0.w += dot4(w, *(const f4*)&sm.u.c.pch[3][m * 64 + sg * 4]);
          pa1.x += dot4(w, *(const f4*)&sm.u.c.pch[4][m * 64 + sg * 4]);
          pa1.y += dot4(w, *(const f4*)&sm.u.c.pch[5][m * 64 + sg * 4]);
          pa1.z += dot4(w, *(const f4*)&sm.u.c.pch[6][m * 64 + sg * 4]);
          pa1.w += dot4(w, *(const f4*)&sm.u.c.pch[7][m * 64 + sg * 4]);
        }
        pa0 = red16v(pa0); pa1 = red16v(pa1);
        if (sg == rr) {   // r == rE here
          sm.u.c.pgc[0][r] = pa0.x + biasE; sm.u.c.pgc[1][r] = pa0.y + biasE;
          sm.u.c.pgc[2][r] = pa0.z + biasE; sm.u.c.pgc[3][r] = pa0.w + biasE;
          sm.u.c.pgc[4][r] = pa1.x + biasE; sm.u.c.pgc[5][r] = pa1.y + biasE;
          sm.u.c.pgc[6][r] = pa1.z + biasE; sm.u.c.pgc[7][r] = pa1.w + biasE;
        }
      }
      __syncthreads();
    }

    // ---- Phase A: wA[h] = whr_w[h].hx + wpc[tau][h] + whr_b[h] ----
    #pragma unroll
    for (int rr = 0; rr < 4; ++rr) {
      const int h = g2 + 64 * rr;
      const float* wrow = whr_w + (size_t)h * HN + sg * 4;
      float a = 0.f;
      #pragma unroll
      for (int m = 0; m < 4; ++m)
        a += dot4(*(const f4*)(wrow + m * 64),
                  *(const f4*)&sm.hx[m * 64 + sg * 4]);
      a = red16(a);
      if (sg == rr) sm.wA[h] = a + sm.u.c.wpc[tau][h] + sm.wrb[h];
    }
    __syncthreads();

    // ---- Phase B: scores[q] = sum_h tanh(wq[q][h] + wA[h]) * w_w[h] ----
    {
      f4 a0 = *(const f4*)&sm.wA[sg * 16 + 0];
      f4 a1 = *(const f4*)&sm.wA[sg * 16 + 4];
      f4 a2 = *(const f4*)&sm.wA[sg * 16 + 8];
      f4 a3 = *(const f4*)&sm.wA[sg * 16 + 12];
      float sc = 0.f;
      sc += fast_tanh(wq0.x + a0.x) * ww0.x;
      sc += fast_tanh(wq0.y + a0.y) * ww0.y;
      sc += fast_tanh(wq0.z + a0.z) * ww0.z;
      sc += fast_tanh(wq0.w + a0.w) * ww0.w;
      sc += fast_tanh(wq1.x + a1.x) * ww1.x;
      sc += fast_tanh(wq1.y + a1.y) * ww1.y;
      sc += fast_tanh(wq1.z + a1.z) * ww1.z;
      sc += fast_tanh(wq1.w + a1.w) * ww1.w;
      sc += fast_tanh(wq2.x + a2.x) * ww2.x;
      sc += fast_tanh(wq2.y + a2.y) * ww2.y;
      sc += fast_tanh(wq2.z + a2.z) * ww2.z;
      sc += fast_tanh(wq2.w + a2.w) * ww2.w;
      sc += fast_tanh(wq3.x + a3.x) * ww3.x;
      sc += fast_tanh(wq3.y + a3.y) * ww3.y;
      sc += fast_tanh(wq3.z + a3.z) * ww3.z;
      sc += fast_tanh(wq3.w + a3.w) * ww3.w;
      sc = red16(sc);
      if (sg == 0) sm.scores[qB] = sc;
    }
    __syncthreads();

    // ---- Phase C: gates[r] = Whh[r].hx (all threads) || softmax (wave 0) ----
    #pragma unroll
    for (int rr = 0; rr < 16; ++rr) {
      const int r = g2 + 64 * rr;
      const float* wrow = Whh + (size_t)r * HN + sg * 4;
      float a = 0.f;
      #pragma unroll
      for (int m = 0; m < 4; ++m)
        a += dot4(*(const f4*)(wrow + m * 64),
                  *(const f4*)&sm.hx[m * 64 + sg * 4]);
      a = red16(a);
      if (sg == rr) sm.gates[r] = a;
    }
    if (t < 64) {  // softmax over q; w_b dropped (shift-invariant)
      float sv = sm.scores[t];
      float mx = sv;
      #pragma unroll
      for (int o = 1; o < 64; o <<= 1) mx = fmaxf(mx, __shfl_xor(mx, o));
      float ex = __builtin_amdgcn_exp2f(1.44269504f * (sv - mx));
      float sum = ex;
      #pragma unroll
      for (int o = 1; o < 64; o <<= 1) sum += __shfl_xor(sum, o);
      sm.al[t] = ex * __builtin_amdgcn_rcpf(sum);
    }
    __syncthreads();

    // ---- Phase D: attn[h] = sum_q al[q] * Q[q][h]  (Q from LDS) ----
    if (t < HN) {
      float a = 0.f;
      #pragma unroll 16
      for (int q = 0; q < QN; ++q)
        a += sm.al[q] * sm.q32[q][t];
      sm.attn[t] = a;
    }
    __syncthreads();

    // ---- Phase E: gates[r] += Wih[r,256:512].attn + pgc[tau][r] ----
    #pragma unroll
    for (int rr = 0; rr < 16; ++rr) {
      const int r = g2 + 64 * rr;
      const float* wrow = Wih + (size_t)r * 512 + 256 + sg * 4;
      float a = 0.f;
      #pragma unroll
      for (int m = 0; m < 4; ++m)
        a += dot4(*(const f4*)(wrow + m * 64),
                  *(const f4*)&sm.attn[m * 64 + sg * 4]);
      a = red16(a);
      if (sg == rr) sm.gates[r] += a + sm.u.c.pgc[tau][r];
    }
    __syncthreads();

    // ---- Phase F: LSTM elementwise + f32 output ----
    if (t < HN) {
      float gi = sm.gates[t], gf = sm.gates[HN + t];
      float gg = sm.gates[2 * HN + t], go = sm.gates[3 * HN + t];
      float c = fast_sig(gf) * sm.cx[t] + fast_sig(gi) * fast_tanh(gg);
      float hn = fast_sig(go) * fast_tanh(c);
      sm.cx[t] = c;
      sm.hx[t] = hn;
      const int trow = tb + ts * s;
      out[((size_t)trow * 64 + b) * 512 + dir * HN + t] = hn;
    }
    __syncthreads();
  }
}

extern "C" void kernel_launch(void* const* d_in, const int* in_sizes, int n_in,
                              void* d_out, int out_size, void* d_ws, size_t ws_size,
                              hipStream_t stream) {
  (void)in_sizes; (void)n_in; (void)out_size; (void)d_ws; (void)ws_size;
  match_kernel<<<dim3(128), dim3(1024), 0, stream>>>(
      (const float*)d_in[0],   // passage
      (const float*)d_in[1],   // question
      (const float*)d_in[2],   // whq_w
      (const float*)d_in[3],   // whq_b
      (const float*)d_in[4],   // whp_w
      (const float*)d_in[5],   // whp_b
      (const float*)d_in[6],   // whr_w
      (const float*)d_in[7],   // whr_b
      (const float*)d_in[8],   // w_w
      (const float*)d_in[10],  // fw_Wih
      (const float*)d_in[11],  // fw_Whh
      (const float*)d_in[12],  // fw_bih
      (const float*)d_in[13],  // fw_bhh
      (const float*)d_in[14],  // bw_Wih
      (const float*)d_in[15],  // bw_Whh
      (const float*)d_in[16],  // bw_bih
      (const float*)d_in[17],  // bw_bhh
      (float*)d_out);
}